// Round 1
// baseline (1503.438 us; speedup 1.0000x reference)
//
#include <hip/hip_runtime.h>
#include <hip/hip_bf16.h>

#define NN 50000
#define NE 800000
#define HD 128

// ---------------- degree / dinv ----------------
__global__ void k_deg_init(float* deg) {
    int i = blockIdx.x * 256 + threadIdx.x;
    if (i < NN) deg[i] = 1.0f;   // self-loop
}

__global__ void k_deg_count(const int* __restrict__ ei, float* deg) {
    int e = blockIdx.x * 256 + threadIdx.x;
    if (e < NE) {
        unsigned d = (unsigned)ei[NE + e];   // dst = edge_index[1]
        if (d < NN) atomicAdd(&deg[d], 1.0f);
    }
}

__global__ void k_rsqrt(float* deg) {
    int i = blockIdx.x * 256 + threadIdx.x;
    if (i < NN) deg[i] = rsqrtf(deg[i]);     // deg >= 1 always
}

// ---------------- GEMM: y = (x @ W) * dinv[n]; acc = y ----------------
// 16 rows/block, 256 threads. W (64KB) + padded x tile in LDS.
__global__ __launch_bounds__(256) void k_gemm_xw(
        const float* __restrict__ x, const float* __restrict__ W,
        const float* __restrict__ dinv,
        float* __restrict__ y, float* __restrict__ acc) {
    __shared__ float Ws[HD * HD];
    __shared__ float xs[16][HD + 1];
    int t = threadIdx.x;
    int rowBase = blockIdx.x * 16;

    const float4* W4 = (const float4*)W;
    float4* Ws4 = (float4*)Ws;
    #pragma unroll
    for (int i = 0; i < (HD * HD / 4) / 256; ++i)
        Ws4[t + i * 256] = W4[t + i * 256];

    #pragma unroll
    for (int i = 0; i < 2; ++i) {
        int idx = t + i * 256;               // float4 index within tile
        int r = (idx * 4) >> 7, c = (idx * 4) & 127;
        float4 v = ((const float4*)x)[((size_t)(rowBase + r) * HD + c) >> 2];
        *(float4*)&xs[r][c] = v;
    }
    __syncthreads();

    int r = t >> 4;            // 0..15
    int cg = t & 15;           // 0..15
    int c0 = cg * 4;           // cols c0..c0+3 and c0+64..c0+67
    float a0x = 0, a0y = 0, a0z = 0, a0w = 0;
    float a1x = 0, a1y = 0, a1z = 0, a1w = 0;
    #pragma unroll 4
    for (int h = 0; h < HD; ++h) {
        float xv = xs[r][h];
        float4 w0 = *(const float4*)&Ws[h * HD + c0];
        float4 w1 = *(const float4*)&Ws[h * HD + c0 + 64];
        a0x += xv * w0.x; a0y += xv * w0.y; a0z += xv * w0.z; a0w += xv * w0.w;
        a1x += xv * w1.x; a1y += xv * w1.y; a1z += xv * w1.z; a1w += xv * w1.w;
    }
    int gr = rowBase + r;
    float dv = dinv[gr];
    float4 o0 = make_float4(a0x * dv, a0y * dv, a0z * dv, a0w * dv);
    float4 o1 = make_float4(a1x * dv, a1y * dv, a1z * dv, a1w * dv);
    size_t base = (size_t)gr * HD;
    *(float4*)&y[base + c0]        = o0;
    *(float4*)&y[base + c0 + 64]   = o1;
    *(float4*)&acc[base + c0]      = o0;
    *(float4*)&acc[base + c0 + 64] = o1;
}

// ---------------- edge scatter: acc[dst] += y[src] ----------------
// 32 lanes per edge, 8 edges per 256-thread block.
__global__ __launch_bounds__(256) void k_scatter(
        const int* __restrict__ ei,
        const float* __restrict__ y, float* __restrict__ acc) {
    int t = threadIdx.x;
    int e = blockIdx.x * 8 + (t >> 5);
    int lane = t & 31;
    if (e >= NE) return;
    unsigned s = (unsigned)ei[e];        // src = edge_index[0]
    unsigned d = (unsigned)ei[NE + e];   // dst = edge_index[1]
    if (s >= NN || d >= NN) return;
    float4 v = *(const float4*)&y[(size_t)s * HD + lane * 4];
    float* ap = &acc[(size_t)d * HD + lane * 4];
    atomicAdd(ap + 0, v.x);
    atomicAdd(ap + 1, v.y);
    atomicAdd(ap + 2, v.z);
    atomicAdd(ap + 3, v.w);
}

// ---------------- z = acc * dinv + b (in place) ----------------
__global__ void k_finalize(float* acc, const float* __restrict__ dinv,
                           const float* __restrict__ b) {
    int i = blockIdx.x * 256 + threadIdx.x;    // float4 groups
    if (i >= NN * (HD / 4)) return;
    int n = i >> 5;
    int c4 = (i & 31) * 4;
    float dv = dinv[n];
    float4 v = *(float4*)&acc[(size_t)n * HD + c4];
    float4 bv = *(const float4*)&b[c4];
    v.x = v.x * dv + bv.x; v.y = v.y * dv + bv.y;
    v.z = v.z * dv + bv.z; v.w = v.w * dv + bv.w;
    *(float4*)&acc[(size_t)n * HD + c4] = v;
}

// ---------------- bilinear: t = z@Wb; pos=<t,z>, neg=<t,z[perm]> ----------------
__global__ __launch_bounds__(256) void k_bilinear(
        const float* __restrict__ z, const float* __restrict__ Wb,
        const float* __restrict__ bb, const int* __restrict__ perm,
        float* __restrict__ out) {
    __shared__ float Ws[HD * HD];
    __shared__ float zs[16][HD + 1];
    int t = threadIdx.x;
    int rowBase = blockIdx.x * 16;

    const float4* W4 = (const float4*)Wb;
    float4* Ws4 = (float4*)Ws;
    #pragma unroll
    for (int i = 0; i < (HD * HD / 4) / 256; ++i)
        Ws4[t + i * 256] = W4[t + i * 256];
    #pragma unroll
    for (int i = 0; i < 2; ++i) {
        int idx = t + i * 256;
        int r = (idx * 4) >> 7, c = (idx * 4) & 127;
        float4 v = ((const float4*)z)[((size_t)(rowBase + r) * HD + c) >> 2];
        *(float4*)&zs[r][c] = v;
    }
    __syncthreads();

    int r = t >> 4;
    int cg = t & 15;
    int c0 = cg * 4;
    float t0x = 0, t0y = 0, t0z = 0, t0w = 0;
    float t1x = 0, t1y = 0, t1z = 0, t1w = 0;
    #pragma unroll 4
    for (int h = 0; h < HD; ++h) {
        float zv = zs[r][h];
        float4 w0 = *(const float4*)&Ws[h * HD + c0];
        float4 w1 = *(const float4*)&Ws[h * HD + c0 + 64];
        t0x += zv * w0.x; t0y += zv * w0.y; t0z += zv * w0.z; t0w += zv * w0.w;
        t1x += zv * w1.x; t1y += zv * w1.y; t1z += zv * w1.z; t1w += zv * w1.w;
    }
    int gr = rowBase + r;
    // positive: dot with own z row (from LDS)
    float pos = t0x * zs[r][c0 + 0] + t0y * zs[r][c0 + 1]
              + t0z * zs[r][c0 + 2] + t0w * zs[r][c0 + 3]
              + t1x * zs[r][c0 + 64] + t1y * zs[r][c0 + 65]
              + t1z * zs[r][c0 + 66] + t1w * zs[r][c0 + 67];
    // negative: dot with z[perm[gr]]
    float neg = 0.0f;
    unsigned p = (unsigned)perm[gr];
    if (p < NN) {
        float4 zp0 = *(const float4*)&z[(size_t)p * HD + c0];
        float4 zp1 = *(const float4*)&z[(size_t)p * HD + c0 + 64];
        neg = t0x * zp0.x + t0y * zp0.y + t0z * zp0.z + t0w * zp0.w
            + t1x * zp1.x + t1y * zp1.y + t1z * zp1.z + t1w * zp1.w;
    }
    #pragma unroll
    for (int off = 8; off; off >>= 1) {
        pos += __shfl_xor(pos, off);
        neg += __shfl_xor(neg, off);
    }
    if (cg == 0) {
        float bbv = bb[0];
        out[gr] = pos + bbv;
        out[NN + gr] = neg + bbv;
    }
}

extern "C" void kernel_launch(void* const* d_in, const int* in_sizes, int n_in,
                              void* d_out, int out_size, void* d_ws, size_t ws_size,
                              hipStream_t stream) {
    const float* x    = (const float*)d_in[0];
    const float* W    = (const float*)d_in[1];
    const float* b    = (const float*)d_in[2];
    const float* Wb   = (const float*)d_in[3];
    const float* bb   = (const float*)d_in[4];
    const int*   ei   = (const int*)d_in[5];
    const int*   perm = (const int*)d_in[6];
    float* out = (float*)d_out;

    char* ws = (char*)d_ws;
    float* dinv = (float*)ws;                                   // N floats
    float* y    = (float*)(ws + 262144);                        // N*128 floats
    float* acc  = (float*)(ws + 262144 + (size_t)NN * HD * 4);  // N*128 floats

    k_deg_init<<<(NN + 255) / 256, 256, 0, stream>>>(dinv);
    k_deg_count<<<(NE + 255) / 256, 256, 0, stream>>>(ei, dinv);
    k_rsqrt<<<(NN + 255) / 256, 256, 0, stream>>>(dinv);
    k_gemm_xw<<<NN / 16, 256, 0, stream>>>(x, W, dinv, y, acc);
    k_scatter<<<NE / 8, 256, 0, stream>>>(ei, y, acc);
    k_finalize<<<(NN * (HD / 4) + 255) / 256, 256, 0, stream>>>(acc, dinv, b);
    k_bilinear<<<NN / 16, 256, 0, stream>>>(acc, Wb, bb, perm, out);
}

// Round 2
// 255.951 us; speedup vs baseline: 5.8739x; 5.8739x over previous
//
#include <hip/hip_runtime.h>
#include <hip/hip_bf16.h>

#define NN 50000
#define NE 800000
#define HD 128

// ---------------- CSR build ----------------
__global__ void k_zero(int* degi, int* total) {
    int i = blockIdx.x * 256 + threadIdx.x;
    if (i < NN) degi[i] = 0;
    if (i == 0) *total = 0;
}

__global__ void k_deg_count(const int* __restrict__ ei, int* degi) {
    int e = blockIdx.x * 256 + threadIdx.x;
    if (e < NE) {
        unsigned d = (unsigned)ei[NE + e];   // dst = edge_index[1]
        if (d < NN) atomicAdd(&degi[d], 1);
    }
}

// per-node: dinv = rsqrt(deg+1); claim contiguous CSR range (order irrelevant)
__global__ void k_rows(const int* __restrict__ degi, float* dinv,
                       int* rowstart, int* cursor, int* total) {
    int n = blockIdx.x * 256 + threadIdx.x;
    if (n >= NN) return;
    int dg = degi[n];
    dinv[n] = rsqrtf((float)(dg + 1));
    int start = atomicAdd(total, dg);
    rowstart[n] = start;
    cursor[n] = start;
}

__global__ void k_bucket(const int* __restrict__ ei, int* cursor, int* csr) {
    int e = blockIdx.x * 256 + threadIdx.x;
    if (e < NE) {
        unsigned s = (unsigned)ei[e];
        unsigned d = (unsigned)ei[NE + e];
        if (s < NN && d < NN) {
            int pos = atomicAdd(&cursor[d], 1);
            csr[pos] = (int)s;
        }
    }
}

// ---------------- GEMM: y = (x @ W) * dinv[n] ----------------
// 16 rows/block, 256 threads. W (64KB) + padded x tile in LDS.
__global__ __launch_bounds__(256) void k_gemm_xw(
        const float* __restrict__ x, const float* __restrict__ W,
        const float* __restrict__ dinv, float* __restrict__ y) {
    __shared__ float Ws[HD * HD];
    __shared__ float xs[16][HD + 1];
    int t = threadIdx.x;
    int rowBase = blockIdx.x * 16;

    const float4* W4 = (const float4*)W;
    float4* Ws4 = (float4*)Ws;
    #pragma unroll
    for (int i = 0; i < (HD * HD / 4) / 256; ++i)
        Ws4[t + i * 256] = W4[t + i * 256];

    #pragma unroll
    for (int i = 0; i < 2; ++i) {
        int idx = t + i * 256;               // float4 index within tile
        int r = (idx * 4) >> 7, c = (idx * 4) & 127;
        float4 v = ((const float4*)x)[((size_t)(rowBase + r) * HD + c) >> 2];
        *(float4*)&xs[r][c] = v;
    }
    __syncthreads();

    int r = t >> 4;            // 0..15
    int cg = t & 15;           // 0..15
    int c0 = cg * 4;           // cols c0..c0+3 and c0+64..c0+67
    float a0x = 0, a0y = 0, a0z = 0, a0w = 0;
    float a1x = 0, a1y = 0, a1z = 0, a1w = 0;
    #pragma unroll 4
    for (int h = 0; h < HD; ++h) {
        float xv = xs[r][h];
        float4 w0 = *(const float4*)&Ws[h * HD + c0];
        float4 w1 = *(const float4*)&Ws[h * HD + c0 + 64];
        a0x += xv * w0.x; a0y += xv * w0.y; a0z += xv * w0.z; a0w += xv * w0.w;
        a1x += xv * w1.x; a1y += xv * w1.y; a1z += xv * w1.z; a1w += xv * w1.w;
    }
    int gr = rowBase + r;
    float dv = dinv[gr];
    size_t base = (size_t)gr * HD;
    *(float4*)&y[base + c0]      = make_float4(a0x * dv, a0y * dv, a0z * dv, a0w * dv);
    *(float4*)&y[base + c0 + 64] = make_float4(a1x * dv, a1y * dv, a1z * dv, a1w * dv);
}

// ---------------- gather: z[n] = dinv[n]*(y[n] + sum_{src->n} y[src]) + b ----------------
// 32 lanes per node (float4/lane covers 128 cols), 8 nodes per 256-thread block.
__global__ __launch_bounds__(256) void k_gather(
        const int* __restrict__ csr, const int* __restrict__ rowstart,
        const int* __restrict__ degi, const float* __restrict__ dinv,
        const float* __restrict__ y, const float* __restrict__ b,
        float* __restrict__ z) {
    int t = threadIdx.x;
    int n = blockIdx.x * 8 + (t >> 5);
    int lane = t & 31;
    if (n >= NN) return;
    int c = lane * 4;

    float4 acc = *(const float4*)&y[(size_t)n * HD + c];   // self-loop term
    int beg = rowstart[n];
    int dg = degi[n];

    int i = 0;
    for (; i + 4 <= dg; i += 4) {           // unroll x4 for MLP
        int s0 = csr[beg + i + 0];
        int s1 = csr[beg + i + 1];
        int s2 = csr[beg + i + 2];
        int s3 = csr[beg + i + 3];
        float4 v0 = *(const float4*)&y[(size_t)s0 * HD + c];
        float4 v1 = *(const float4*)&y[(size_t)s1 * HD + c];
        float4 v2 = *(const float4*)&y[(size_t)s2 * HD + c];
        float4 v3 = *(const float4*)&y[(size_t)s3 * HD + c];
        acc.x += v0.x + v1.x + v2.x + v3.x;
        acc.y += v0.y + v1.y + v2.y + v3.y;
        acc.z += v0.z + v1.z + v2.z + v3.z;
        acc.w += v0.w + v1.w + v2.w + v3.w;
    }
    for (; i < dg; ++i) {
        int s = csr[beg + i];
        float4 v = *(const float4*)&y[(size_t)s * HD + c];
        acc.x += v.x; acc.y += v.y; acc.z += v.z; acc.w += v.w;
    }

    float dv = dinv[n];
    float4 bv = *(const float4*)&b[c];
    acc.x = acc.x * dv + bv.x;
    acc.y = acc.y * dv + bv.y;
    acc.z = acc.z * dv + bv.z;
    acc.w = acc.w * dv + bv.w;
    *(float4*)&z[(size_t)n * HD + c] = acc;
}

// ---------------- bilinear: t = z@Wb; pos=<t,z>, neg=<t,z[perm]> ----------------
__global__ __launch_bounds__(256) void k_bilinear(
        const float* __restrict__ z, const float* __restrict__ Wb,
        const float* __restrict__ bb, const int* __restrict__ perm,
        float* __restrict__ out) {
    __shared__ float Ws[HD * HD];
    __shared__ float zs[16][HD + 1];
    int t = threadIdx.x;
    int rowBase = blockIdx.x * 16;

    const float4* W4 = (const float4*)Wb;
    float4* Ws4 = (float4*)Ws;
    #pragma unroll
    for (int i = 0; i < (HD * HD / 4) / 256; ++i)
        Ws4[t + i * 256] = W4[t + i * 256];
    #pragma unroll
    for (int i = 0; i < 2; ++i) {
        int idx = t + i * 256;
        int r = (idx * 4) >> 7, c = (idx * 4) & 127;
        float4 v = ((const float4*)z)[((size_t)(rowBase + r) * HD + c) >> 2];
        *(float4*)&zs[r][c] = v;
    }
    __syncthreads();

    int r = t >> 4;
    int cg = t & 15;
    int c0 = cg * 4;
    float t0x = 0, t0y = 0, t0z = 0, t0w = 0;
    float t1x = 0, t1y = 0, t1z = 0, t1w = 0;
    #pragma unroll 4
    for (int h = 0; h < HD; ++h) {
        float zv = zs[r][h];
        float4 w0 = *(const float4*)&Ws[h * HD + c0];
        float4 w1 = *(const float4*)&Ws[h * HD + c0 + 64];
        t0x += zv * w0.x; t0y += zv * w0.y; t0z += zv * w0.z; t0w += zv * w0.w;
        t1x += zv * w1.x; t1y += zv * w1.y; t1z += zv * w1.z; t1w += zv * w1.w;
    }
    int gr = rowBase + r;
    float pos = t0x * zs[r][c0 + 0] + t0y * zs[r][c0 + 1]
              + t0z * zs[r][c0 + 2] + t0w * zs[r][c0 + 3]
              + t1x * zs[r][c0 + 64] + t1y * zs[r][c0 + 65]
              + t1z * zs[r][c0 + 66] + t1w * zs[r][c0 + 67];
    float neg = 0.0f;
    unsigned p = (unsigned)perm[gr];
    if (p < NN) {
        float4 zp0 = *(const float4*)&z[(size_t)p * HD + c0];
        float4 zp1 = *(const float4*)&z[(size_t)p * HD + c0 + 64];
        neg = t0x * zp0.x + t0y * zp0.y + t0z * zp0.z + t0w * zp0.w
            + t1x * zp1.x + t1y * zp1.y + t1z * zp1.z + t1w * zp1.w;
    }
    #pragma unroll
    for (int off = 8; off; off >>= 1) {
        pos += __shfl_xor(pos, off);
        neg += __shfl_xor(neg, off);
    }
    if (cg == 0) {
        float bbv = bb[0];
        out[gr] = pos + bbv;
        out[NN + gr] = neg + bbv;
    }
}

extern "C" void kernel_launch(void* const* d_in, const int* in_sizes, int n_in,
                              void* d_out, int out_size, void* d_ws, size_t ws_size,
                              hipStream_t stream) {
    const float* x    = (const float*)d_in[0];
    const float* W    = (const float*)d_in[1];
    const float* b    = (const float*)d_in[2];
    const float* Wb   = (const float*)d_in[3];
    const float* bb   = (const float*)d_in[4];
    const int*   ei   = (const int*)d_in[5];
    const int*   perm = (const int*)d_in[6];
    float* out = (float*)d_out;

    char* ws = (char*)d_ws;
    int*   degi     = (int*)(ws + 0);                     // 200 KB
    int*   rowstart = (int*)(ws + (256 << 10));           // 200 KB
    int*   cursor   = (int*)(ws + (512 << 10));           // 200 KB
    int*   total    = (int*)(ws + (768 << 10));           // 4 B
    float* dinv     = (float*)(ws + (1024 << 10));        // 200 KB
    int*   csr      = (int*)(ws + (1280 << 10));          // 3.2 MB
    float* y        = (float*)(ws + (4608 << 10));        // 25.6 MB
    float* z        = (float*)(ws + (4608 << 10) + (size_t)NN * HD * 4);

    k_zero<<<(NN + 255) / 256, 256, 0, stream>>>(degi, total);
    k_deg_count<<<(NE + 255) / 256, 256, 0, stream>>>(ei, degi);
    k_rows<<<(NN + 255) / 256, 256, 0, stream>>>(degi, dinv, rowstart, cursor, total);
    k_bucket<<<(NE + 255) / 256, 256, 0, stream>>>(ei, cursor, csr);
    k_gemm_xw<<<NN / 16, 256, 0, stream>>>(x, W, dinv, y);
    k_gather<<<(NN + 7) / 8, 256, 0, stream>>>(csr, rowstart, degi, dinv, y, b, z);
    k_bilinear<<<NN / 16, 256, 0, stream>>>(z, Wb, bb, perm, out);
}

// Round 3
// 184.441 us; speedup vs baseline: 8.1513x; 1.3877x over previous
//
#include <hip/hip_runtime.h>
#include <hip/hip_bf16.h>

#define NN 50000
#define NE 800000
#define HD 128

#define BINSH 9                 // 512 nodes per coarse bin
#define NBINS 98                // ceil(50000/512)
#define BINCAP 9216             // slop capacity (mean 8163, 11.6 sigma)
#define CHUNK 4096              // edges per binplace block
#define MAXBIN 9216

// ---------------- init bin cursors ----------------
__global__ void k_init(int* cursor) {
    int t = threadIdx.x;
    if (t < NBINS) cursor[t] = t * BINCAP;
}

// ---------------- pass 1: bin edges by dst>>9, coalesced writes ----------------
__global__ __launch_bounds__(256) void k_binplace(
        const int* __restrict__ ei, int* cursor, unsigned* __restrict__ binned) {
    __shared__ unsigned stage[CHUNK];
    __shared__ unsigned char sbin[CHUNK];
    __shared__ int hist[NBINS], base[NBINS], cur[NBINS], gbase[NBINS];
    int t = threadIdx.x;
    int e0 = blockIdx.x * CHUNK;
    int nE = NE - e0; if (nE > CHUNK) nE = CHUNK;

    if (t < NBINS) hist[t] = 0;
    __syncthreads();

    unsigned keys[16], packs[16];
    #pragma unroll
    for (int i = 0; i < 16; ++i) {
        int li = i * 256 + t;
        keys[i] = 0xffffffffu;
        if (li < nE) {
            int e = e0 + li;
            unsigned s = (unsigned)ei[e];
            unsigned d = (unsigned)ei[NE + e];
            if (s < NN && d < NN) {
                keys[i] = d >> BINSH;
                packs[i] = (s << BINSH) | (d & ((1u << BINSH) - 1));
                atomicAdd(&hist[keys[i]], 1);
            }
        }
    }
    __syncthreads();
    if (t == 0) { int a = 0; for (int b = 0; b < NBINS; ++b) { base[b] = a; a += hist[b]; } }
    __syncthreads();
    if (t < NBINS) {
        cur[t] = base[t];
        if (hist[t] > 0) gbase[t] = atomicAdd(&cursor[t], hist[t]);
    }
    __syncthreads();
    #pragma unroll
    for (int i = 0; i < 16; ++i) {
        if (keys[i] != 0xffffffffu) {
            int p = atomicAdd(&cur[keys[i]], 1);
            stage[p] = packs[i];
            sbin[p] = (unsigned char)keys[i];
        }
    }
    __syncthreads();
    int tot = cur[NBINS - 1];   // == number of valid edges staged
    for (int j = t; j < tot; j += 256) {
        unsigned b = sbin[j];
        binned[gbase[b] + (j - base[b])] = stage[j];
    }
}

// ---------------- pass 2: per-bin sort -> CSR (u16 src), deg/dinv/rowstart ----------------
__global__ __launch_bounds__(256) void k_csr(
        const unsigned* __restrict__ binned, const int* __restrict__ cursor,
        unsigned short* __restrict__ csr, int* __restrict__ rowstart,
        int* __restrict__ degi, float* __restrict__ dinv) {
    __shared__ unsigned ent[MAXBIN];
    __shared__ unsigned short outv[MAXBIN];
    __shared__ int hist[512], rs[512], cur[512];
    __shared__ int sizes[NBINS];
    int t = threadIdx.x, b = blockIdx.x;

    if (t < NBINS) sizes[t] = cursor[t] - t * BINCAP;
    __syncthreads();
    int bsize = sizes[b]; if (bsize > MAXBIN) bsize = MAXBIN;
    int bstart = 0;
    for (int i = 0; i < b; ++i) bstart += sizes[i];

    for (int j = t; j < bsize; j += 256) ent[j] = binned[b * BINCAP + j];
    for (int k = t; k < 512; k += 256) hist[k] = 0;
    __syncthreads();
    for (int j = t; j < bsize; j += 256) atomicAdd(&hist[ent[j] & 511], 1);
    __syncthreads();
    if (t == 0) { int a = 0; for (int k = 0; k < 512; ++k) { rs[k] = a; a += hist[k]; } }
    __syncthreads();
    for (int k = t; k < 512; k += 256) {
        cur[k] = rs[k];
        int g = (b << BINSH) + k;
        if (g < NN) {
            rowstart[g] = bstart + rs[k];
            degi[g] = hist[k];
            dinv[g] = rsqrtf((float)(hist[k] + 1));
        }
    }
    __syncthreads();
    for (int j = t; j < bsize; j += 256) {
        unsigned v = ent[j];
        int p = atomicAdd(&cur[v & 511], 1);
        outv[p] = (unsigned short)(v >> BINSH);
    }
    __syncthreads();
    for (int j = t; j < bsize; j += 256) csr[bstart + j] = outv[j];
}

// ---------------- GEMM: y = (x @ W) * dinv[n] ----------------
__global__ __launch_bounds__(256) void k_gemm_xw(
        const float* __restrict__ x, const float* __restrict__ W,
        const float* __restrict__ dinv, float* __restrict__ y) {
    __shared__ float Ws[HD * HD];
    __shared__ float xs[16][HD + 1];
    int t = threadIdx.x;
    int rowBase = blockIdx.x * 16;

    const float4* W4 = (const float4*)W;
    float4* Ws4 = (float4*)Ws;
    #pragma unroll
    for (int i = 0; i < (HD * HD / 4) / 256; ++i)
        Ws4[t + i * 256] = W4[t + i * 256];
    #pragma unroll
    for (int i = 0; i < 2; ++i) {
        int idx = t + i * 256;
        int r = (idx * 4) >> 7, c = (idx * 4) & 127;
        float4 v = ((const float4*)x)[((size_t)(rowBase + r) * HD + c) >> 2];
        *(float4*)&xs[r][c] = v;
    }
    __syncthreads();

    int r = t >> 4;
    int cg = t & 15;
    int c0 = cg * 4;
    float a0x = 0, a0y = 0, a0z = 0, a0w = 0;
    float a1x = 0, a1y = 0, a1z = 0, a1w = 0;
    #pragma unroll 4
    for (int h = 0; h < HD; ++h) {
        float xv = xs[r][h];
        float4 w0 = *(const float4*)&Ws[h * HD + c0];
        float4 w1 = *(const float4*)&Ws[h * HD + c0 + 64];
        a0x += xv * w0.x; a0y += xv * w0.y; a0z += xv * w0.z; a0w += xv * w0.w;
        a1x += xv * w1.x; a1y += xv * w1.y; a1z += xv * w1.z; a1w += xv * w1.w;
    }
    int gr = rowBase + r;
    float dv = dinv[gr];
    size_t basei = (size_t)gr * HD;
    *(float4*)&y[basei + c0]      = make_float4(a0x * dv, a0y * dv, a0z * dv, a0w * dv);
    *(float4*)&y[basei + c0 + 64] = make_float4(a1x * dv, a1y * dv, a1z * dv, a1w * dv);
}

// ---------------- gather: z[n] = dinv[n]*(y[n] + sum y[src]) + b ----------------
__global__ __launch_bounds__(256) void k_gather(
        const unsigned short* __restrict__ csr, const int* __restrict__ rowstart,
        const int* __restrict__ degi, const float* __restrict__ dinv,
        const float* __restrict__ y, const float* __restrict__ b,
        float* __restrict__ z) {
    int t = threadIdx.x;
    int n = blockIdx.x * 8 + (t >> 5);
    int lane = t & 31;
    if (n >= NN) return;
    int c = lane * 4;

    float4 acc = *(const float4*)&y[(size_t)n * HD + c];
    int beg = rowstart[n];
    int dg = degi[n];

    int i = 0;
    for (; i + 4 <= dg; i += 4) {
        int s0 = csr[beg + i + 0];
        int s1 = csr[beg + i + 1];
        int s2 = csr[beg + i + 2];
        int s3 = csr[beg + i + 3];
        float4 v0 = *(const float4*)&y[(size_t)s0 * HD + c];
        float4 v1 = *(const float4*)&y[(size_t)s1 * HD + c];
        float4 v2 = *(const float4*)&y[(size_t)s2 * HD + c];
        float4 v3 = *(const float4*)&y[(size_t)s3 * HD + c];
        acc.x += v0.x + v1.x + v2.x + v3.x;
        acc.y += v0.y + v1.y + v2.y + v3.y;
        acc.z += v0.z + v1.z + v2.z + v3.z;
        acc.w += v0.w + v1.w + v2.w + v3.w;
    }
    for (; i < dg; ++i) {
        int s = csr[beg + i];
        float4 v = *(const float4*)&y[(size_t)s * HD + c];
        acc.x += v.x; acc.y += v.y; acc.z += v.z; acc.w += v.w;
    }

    float dv = dinv[n];
    float4 bv = *(const float4*)&b[c];
    acc.x = acc.x * dv + bv.x;
    acc.y = acc.y * dv + bv.y;
    acc.z = acc.z * dv + bv.z;
    acc.w = acc.w * dv + bv.w;
    *(float4*)&z[(size_t)n * HD + c] = acc;
}

// ---------------- bilinear ----------------
__global__ __launch_bounds__(256) void k_bilinear(
        const float* __restrict__ z, const float* __restrict__ Wb,
        const float* __restrict__ bb, const int* __restrict__ perm,
        float* __restrict__ out) {
    __shared__ float Ws[HD * HD];
    __shared__ float zs[16][HD + 1];
    int t = threadIdx.x;
    int rowBase = blockIdx.x * 16;

    const float4* W4 = (const float4*)Wb;
    float4* Ws4 = (float4*)Ws;
    #pragma unroll
    for (int i = 0; i < (HD * HD / 4) / 256; ++i)
        Ws4[t + i * 256] = W4[t + i * 256];
    #pragma unroll
    for (int i = 0; i < 2; ++i) {
        int idx = t + i * 256;
        int r = (idx * 4) >> 7, c = (idx * 4) & 127;
        float4 v = ((const float4*)z)[((size_t)(rowBase + r) * HD + c) >> 2];
        *(float4*)&zs[r][c] = v;
    }
    __syncthreads();

    int r = t >> 4;
    int cg = t & 15;
    int c0 = cg * 4;
    float t0x = 0, t0y = 0, t0z = 0, t0w = 0;
    float t1x = 0, t1y = 0, t1z = 0, t1w = 0;
    #pragma unroll 4
    for (int h = 0; h < HD; ++h) {
        float zv = zs[r][h];
        float4 w0 = *(const float4*)&Ws[h * HD + c0];
        float4 w1 = *(const float4*)&Ws[h * HD + c0 + 64];
        t0x += zv * w0.x; t0y += zv * w0.y; t0z += zv * w0.z; t0w += zv * w0.w;
        t1x += zv * w1.x; t1y += zv * w1.y; t1z += zv * w1.z; t1w += zv * w1.w;
    }
    int gr = rowBase + r;
    float pos = t0x * zs[r][c0 + 0] + t0y * zs[r][c0 + 1]
              + t0z * zs[r][c0 + 2] + t0w * zs[r][c0 + 3]
              + t1x * zs[r][c0 + 64] + t1y * zs[r][c0 + 65]
              + t1z * zs[r][c0 + 66] + t1w * zs[r][c0 + 67];
    float neg = 0.0f;
    unsigned p = (unsigned)perm[gr];
    if (p < NN) {
        float4 zp0 = *(const float4*)&z[(size_t)p * HD + c0];
        float4 zp1 = *(const float4*)&z[(size_t)p * HD + c0 + 64];
        neg = t0x * zp0.x + t0y * zp0.y + t0z * zp0.z + t0w * zp0.w
            + t1x * zp1.x + t1y * zp1.y + t1z * zp1.z + t1w * zp1.w;
    }
    #pragma unroll
    for (int off = 8; off; off >>= 1) {
        pos += __shfl_xor(pos, off);
        neg += __shfl_xor(neg, off);
    }
    if (cg == 0) {
        float bbv = bb[0];
        out[gr] = pos + bbv;
        out[NN + gr] = neg + bbv;
    }
}

extern "C" void kernel_launch(void* const* d_in, const int* in_sizes, int n_in,
                              void* d_out, int out_size, void* d_ws, size_t ws_size,
                              hipStream_t stream) {
    const float* x    = (const float*)d_in[0];
    const float* W    = (const float*)d_in[1];
    const float* b    = (const float*)d_in[2];
    const float* Wb   = (const float*)d_in[3];
    const float* bb   = (const float*)d_in[4];
    const int*   ei   = (const int*)d_in[5];
    const int*   perm = (const int*)d_in[6];
    float* out = (float*)d_out;

    char* ws = (char*)d_ws;
    int*            cursor   = (int*)(ws + 0);               // 4 KB
    float*          dinv     = (float*)(ws + 0x1000);        // 200 KB
    int*            rowstart = (int*)(ws + 0x33000);         // 200 KB
    int*            degi     = (int*)(ws + 0x65000);         // 200 KB
    unsigned short* csr      = (unsigned short*)(ws + 0x97000);   // 1.6 MB
    unsigned*       binned   = (unsigned*)(ws + 0x240000);   // 3.6 MB
    float*          y        = (float*)(ws + 0x600000);      // 25.6 MB
    float*          z        = (float*)(ws + 0x2000000);     // 25.6 MB

    k_init<<<1, 128, 0, stream>>>(cursor);
    k_binplace<<<(NE + CHUNK - 1) / CHUNK, 256, 0, stream>>>(ei, cursor, binned);
    k_csr<<<NBINS, 256, 0, stream>>>(binned, cursor, csr, rowstart, degi, dinv);
    k_gemm_xw<<<NN / 16, 256, 0, stream>>>(x, W, dinv, y);
    k_gather<<<(NN + 7) / 8, 256, 0, stream>>>(csr, rowstart, degi, dinv, y, b, z);
    k_bilinear<<<NN / 16, 256, 0, stream>>>(z, Wb, bb, perm, out);
}

// Round 4
// 159.560 us; speedup vs baseline: 9.4224x; 1.1559x over previous
//
#include <hip/hip_runtime.h>
#include <hip/hip_bf16.h>

#define NN 50000
#define NE 800000
#define HD 128

#define BINSH 9                 // 512 nodes per coarse bin
#define NBINS 98                // ceil(50000/512)
#define BINCAP 9216             // slop capacity (mean 8163, 11.6 sigma)
#define CHUNK 4096              // edges per binplace block
#define MAXBIN 9216

// f32 -> bf16 round-to-nearest-even
__device__ inline unsigned short f2bf(float f) {
    union { float f; unsigned u; } c; c.f = f;
    unsigned r = c.u + 0x7fff + ((c.u >> 16) & 1);
    return (unsigned short)(r >> 16);
}

// load 4 bf16 (8B) -> float4
__device__ inline float4 ld_bf4(const unsigned short* p) {
    uint2 q = *(const uint2*)p;
    float4 r;
    r.x = __uint_as_float(q.x << 16);
    r.y = __uint_as_float(q.x & 0xffff0000u);
    r.z = __uint_as_float(q.y << 16);
    r.w = __uint_as_float(q.y & 0xffff0000u);
    return r;
}

// ---------------- init bin cursors ----------------
__global__ void k_init(int* cursor) {
    int t = threadIdx.x;
    if (t < NBINS) cursor[t] = t * BINCAP;
}

// ---------------- pass 1: bin edges by dst>>9, coalesced writes ----------------
__global__ __launch_bounds__(256) void k_binplace(
        const int* __restrict__ ei, int* cursor, unsigned* __restrict__ binned) {
    __shared__ unsigned stage[CHUNK];
    __shared__ unsigned char sbin[CHUNK];
    __shared__ int hist[NBINS], base[NBINS], cur[NBINS], gbase[NBINS];
    int t = threadIdx.x;
    int e0 = blockIdx.x * CHUNK;
    int nE = NE - e0; if (nE > CHUNK) nE = CHUNK;

    if (t < NBINS) hist[t] = 0;
    __syncthreads();

    unsigned keys[16], packs[16];
    #pragma unroll
    for (int i = 0; i < 16; ++i) {
        int li = i * 256 + t;
        keys[i] = 0xffffffffu;
        if (li < nE) {
            int e = e0 + li;
            unsigned s = (unsigned)ei[e];
            unsigned d = (unsigned)ei[NE + e];
            if (s < NN && d < NN) {
                keys[i] = d >> BINSH;
                packs[i] = (s << BINSH) | (d & ((1u << BINSH) - 1));
                atomicAdd(&hist[keys[i]], 1);
            }
        }
    }
    __syncthreads();
    if (t == 0) { int a = 0; for (int b = 0; b < NBINS; ++b) { base[b] = a; a += hist[b]; } }
    __syncthreads();
    if (t < NBINS) {
        cur[t] = base[t];
        if (hist[t] > 0) gbase[t] = atomicAdd(&cursor[t], hist[t]);
    }
    __syncthreads();
    #pragma unroll
    for (int i = 0; i < 16; ++i) {
        if (keys[i] != 0xffffffffu) {
            int p = atomicAdd(&cur[keys[i]], 1);
            stage[p] = packs[i];
            sbin[p] = (unsigned char)keys[i];
        }
    }
    __syncthreads();
    int tot = cur[NBINS - 1];   // == number of valid edges staged
    for (int j = t; j < tot; j += 256) {
        unsigned b = sbin[j];
        binned[gbase[b] + (j - base[b])] = stage[j];
    }
}

// ---------------- pass 2: per-bin sort -> CSR (u16 src), deg/dinv/rowstart ----------------
__global__ __launch_bounds__(256) void k_csr(
        const unsigned* __restrict__ binned, const int* __restrict__ cursor,
        unsigned short* __restrict__ csr, int* __restrict__ rowstart,
        int* __restrict__ degi, float* __restrict__ dinv) {
    __shared__ unsigned ent[MAXBIN];
    __shared__ unsigned short outv[MAXBIN];
    __shared__ int hist[512], rs[512], cur[512];
    __shared__ int sizes[NBINS];
    int t = threadIdx.x, b = blockIdx.x;

    if (t < NBINS) sizes[t] = cursor[t] - t * BINCAP;
    __syncthreads();
    int bsize = sizes[b]; if (bsize > MAXBIN) bsize = MAXBIN;
    int bstart = 0;
    for (int i = 0; i < b; ++i) bstart += sizes[i];

    for (int j = t; j < bsize; j += 256) ent[j] = binned[b * BINCAP + j];
    for (int k = t; k < 512; k += 256) hist[k] = 0;
    __syncthreads();
    for (int j = t; j < bsize; j += 256) atomicAdd(&hist[ent[j] & 511], 1);
    __syncthreads();
    if (t == 0) { int a = 0; for (int k = 0; k < 512; ++k) { rs[k] = a; a += hist[k]; } }
    __syncthreads();
    for (int k = t; k < 512; k += 256) {
        cur[k] = rs[k];
        int g = (b << BINSH) + k;
        if (g < NN) {
            rowstart[g] = bstart + rs[k];
            degi[g] = hist[k];
            dinv[g] = rsqrtf((float)(hist[k] + 1));
        }
    }
    __syncthreads();
    for (int j = t; j < bsize; j += 256) {
        unsigned v = ent[j];
        int p = atomicAdd(&cur[v & 511], 1);
        outv[p] = (unsigned short)(v >> BINSH);
    }
    __syncthreads();
    for (int j = t; j < bsize; j += 256) csr[bstart + j] = outv[j];
}

// ---------------- GEMM: ybf = bf16((x @ W) * dinv[n]) ----------------
__global__ __launch_bounds__(256) void k_gemm_xw(
        const float* __restrict__ x, const float* __restrict__ W,
        const float* __restrict__ dinv, unsigned short* __restrict__ ybf) {
    __shared__ float Ws[HD * HD];
    __shared__ float xs[16][HD + 1];
    int t = threadIdx.x;
    int rowBase = blockIdx.x * 16;

    const float4* W4 = (const float4*)W;
    float4* Ws4 = (float4*)Ws;
    #pragma unroll
    for (int i = 0; i < (HD * HD / 4) / 256; ++i)
        Ws4[t + i * 256] = W4[t + i * 256];
    #pragma unroll
    for (int i = 0; i < 2; ++i) {
        int idx = t + i * 256;
        int r = (idx * 4) >> 7, c = (idx * 4) & 127;
        float4 v = ((const float4*)x)[((size_t)(rowBase + r) * HD + c) >> 2];
        *(float4*)&xs[r][c] = v;
    }
    __syncthreads();

    int r = t >> 4;
    int cg = t & 15;
    int c0 = cg * 4;
    float a0x = 0, a0y = 0, a0z = 0, a0w = 0;
    float a1x = 0, a1y = 0, a1z = 0, a1w = 0;
    #pragma unroll 4
    for (int h = 0; h < HD; ++h) {
        float xv = xs[r][h];
        float4 w0 = *(const float4*)&Ws[h * HD + c0];
        float4 w1 = *(const float4*)&Ws[h * HD + c0 + 64];
        a0x += xv * w0.x; a0y += xv * w0.y; a0z += xv * w0.z; a0w += xv * w0.w;
        a1x += xv * w1.x; a1y += xv * w1.y; a1z += xv * w1.z; a1w += xv * w1.w;
    }
    int gr = rowBase + r;
    float dv = dinv[gr];
    size_t basei = (size_t)gr * HD;
    ushort4 p0, p1;
    p0.x = f2bf(a0x * dv); p0.y = f2bf(a0y * dv); p0.z = f2bf(a0z * dv); p0.w = f2bf(a0w * dv);
    p1.x = f2bf(a1x * dv); p1.y = f2bf(a1y * dv); p1.z = f2bf(a1z * dv); p1.w = f2bf(a1w * dv);
    *(ushort4*)&ybf[basei + c0]      = p0;
    *(ushort4*)&ybf[basei + c0 + 64] = p1;
}

// ---------------- gather: z[n] = dinv[n]*(y[n] + sum y[src]) + b ----------------
__global__ __launch_bounds__(256) void k_gather(
        const unsigned short* __restrict__ csr, const int* __restrict__ rowstart,
        const int* __restrict__ degi, const float* __restrict__ dinv,
        const unsigned short* __restrict__ ybf, const float* __restrict__ b,
        float* __restrict__ z) {
    int t = threadIdx.x;
    int n = blockIdx.x * 8 + (t >> 5);
    int lane = t & 31;
    if (n >= NN) return;
    int c = lane * 4;

    float4 acc = ld_bf4(&ybf[(size_t)n * HD + c]);   // self-loop term
    int beg = rowstart[n];
    int dg = degi[n];

    int i = 0;
    for (; i + 4 <= dg; i += 4) {
        int s0 = csr[beg + i + 0];
        int s1 = csr[beg + i + 1];
        int s2 = csr[beg + i + 2];
        int s3 = csr[beg + i + 3];
        float4 v0 = ld_bf4(&ybf[(size_t)s0 * HD + c]);
        float4 v1 = ld_bf4(&ybf[(size_t)s1 * HD + c]);
        float4 v2 = ld_bf4(&ybf[(size_t)s2 * HD + c]);
        float4 v3 = ld_bf4(&ybf[(size_t)s3 * HD + c]);
        acc.x += v0.x + v1.x + v2.x + v3.x;
        acc.y += v0.y + v1.y + v2.y + v3.y;
        acc.z += v0.z + v1.z + v2.z + v3.z;
        acc.w += v0.w + v1.w + v2.w + v3.w;
    }
    for (; i < dg; ++i) {
        int s = csr[beg + i];
        float4 v = ld_bf4(&ybf[(size_t)s * HD + c]);
        acc.x += v.x; acc.y += v.y; acc.z += v.z; acc.w += v.w;
    }

    float dv = dinv[n];
    float4 bv = *(const float4*)&b[c];
    acc.x = acc.x * dv + bv.x;
    acc.y = acc.y * dv + bv.y;
    acc.z = acc.z * dv + bv.z;
    acc.w = acc.w * dv + bv.w;
    *(float4*)&z[(size_t)n * HD + c] = acc;
}

// ---------------- bilinear ----------------
__global__ __launch_bounds__(256) void k_bilinear(
        const float* __restrict__ z, const float* __restrict__ Wb,
        const float* __restrict__ bb, const int* __restrict__ perm,
        float* __restrict__ out) {
    __shared__ float Ws[HD * HD];
    __shared__ float zs[16][HD + 1];
    int t = threadIdx.x;
    int rowBase = blockIdx.x * 16;

    const float4* W4 = (const float4*)Wb;
    float4* Ws4 = (float4*)Ws;
    #pragma unroll
    for (int i = 0; i < (HD * HD / 4) / 256; ++i)
        Ws4[t + i * 256] = W4[t + i * 256];
    #pragma unroll
    for (int i = 0; i < 2; ++i) {
        int idx = t + i * 256;
        int r = (idx * 4) >> 7, c = (idx * 4) & 127;
        float4 v = ((const float4*)z)[((size_t)(rowBase + r) * HD + c) >> 2];
        *(float4*)&zs[r][c] = v;
    }
    __syncthreads();

    int r = t >> 4;
    int cg = t & 15;
    int c0 = cg * 4;
    float t0x = 0, t0y = 0, t0z = 0, t0w = 0;
    float t1x = 0, t1y = 0, t1z = 0, t1w = 0;
    #pragma unroll 4
    for (int h = 0; h < HD; ++h) {
        float zv = zs[r][h];
        float4 w0 = *(const float4*)&Ws[h * HD + c0];
        float4 w1 = *(const float4*)&Ws[h * HD + c0 + 64];
        t0x += zv * w0.x; t0y += zv * w0.y; t0z += zv * w0.z; t0w += zv * w0.w;
        t1x += zv * w1.x; t1y += zv * w1.y; t1z += zv * w1.z; t1w += zv * w1.w;
    }
    int gr = rowBase + r;
    float pos = t0x * zs[r][c0 + 0] + t0y * zs[r][c0 + 1]
              + t0z * zs[r][c0 + 2] + t0w * zs[r][c0 + 3]
              + t1x * zs[r][c0 + 64] + t1y * zs[r][c0 + 65]
              + t1z * zs[r][c0 + 66] + t1w * zs[r][c0 + 67];
    float neg = 0.0f;
    unsigned p = (unsigned)perm[gr];
    if (p < NN) {
        float4 zp0 = *(const float4*)&z[(size_t)p * HD + c0];
        float4 zp1 = *(const float4*)&z[(size_t)p * HD + c0 + 64];
        neg = t0x * zp0.x + t0y * zp0.y + t0z * zp0.z + t0w * zp0.w
            + t1x * zp1.x + t1y * zp1.y + t1z * zp1.z + t1w * zp1.w;
    }
    #pragma unroll
    for (int off = 8; off; off >>= 1) {
        pos += __shfl_xor(pos, off);
        neg += __shfl_xor(neg, off);
    }
    if (cg == 0) {
        float bbv = bb[0];
        out[gr] = pos + bbv;
        out[NN + gr] = neg + bbv;
    }
}

extern "C" void kernel_launch(void* const* d_in, const int* in_sizes, int n_in,
                              void* d_out, int out_size, void* d_ws, size_t ws_size,
                              hipStream_t stream) {
    const float* x    = (const float*)d_in[0];
    const float* W    = (const float*)d_in[1];
    const float* b    = (const float*)d_in[2];
    const float* Wb   = (const float*)d_in[3];
    const float* bb   = (const float*)d_in[4];
    const int*   ei   = (const int*)d_in[5];
    const int*   perm = (const int*)d_in[6];
    float* out = (float*)d_out;

    char* ws = (char*)d_ws;
    int*            cursor   = (int*)(ws + 0);               // 4 KB
    float*          dinv     = (float*)(ws + 0x1000);        // 200 KB
    int*            rowstart = (int*)(ws + 0x33000);         // 200 KB
    int*            degi     = (int*)(ws + 0x65000);         // 200 KB
    unsigned short* csr      = (unsigned short*)(ws + 0x97000);   // 1.6 MB
    unsigned*       binned   = (unsigned*)(ws + 0x240000);   // 3.6 MB
    unsigned short* ybf      = (unsigned short*)(ws + 0x600000);  // 12.8 MB
    float*          z        = (float*)(ws + 0x2000000);     // 25.6 MB

    k_init<<<1, 128, 0, stream>>>(cursor);
    k_binplace<<<(NE + CHUNK - 1) / CHUNK, 256, 0, stream>>>(ei, cursor, binned);
    k_csr<<<NBINS, 256, 0, stream>>>(binned, cursor, csr, rowstart, degi, dinv);
    k_gemm_xw<<<NN / 16, 256, 0, stream>>>(x, W, dinv, ybf);
    k_gather<<<(NN + 7) / 8, 256, 0, stream>>>(csr, rowstart, degi, dinv, ybf, b, z);
    k_bilinear<<<NN / 16, 256, 0, stream>>>(z, Wb, bb, perm, out);
}